// Round 14
// baseline (3745.972 us; speedup 1.0000x reference)
//
#include <hip/hip_runtime.h>
#include <hip/hip_bf16.h>

// Problem constants (match reference)
#define NN 20000
#define EE 320000
#define DD 3072
#define HH 1536
#define LL 64

typedef unsigned short bf16_t;
typedef __attribute__((ext_vector_type(8))) __bf16 bf16x8;
typedef __attribute__((ext_vector_type(4))) float  f32x4;

__device__ __forceinline__ bf16_t f2bf(float f) {
    union { float f; unsigned u; } c; c.f = f;
    unsigned u = c.u;
    return (bf16_t)((u + 0x7fffu + ((u >> 16) & 1u)) >> 16);  // RNE (inputs finite)
}

// ---------------------------------------------------------------------------
// CSR build. edge_index is int32: src = ei[e], dst = ei[E+e].
// ---------------------------------------------------------------------------
__global__ void zero_int(int* __restrict__ p, int n) {
    int i = blockIdx.x * blockDim.x + threadIdx.x;
    if (i < n) p[i] = 0;
}

__global__ void cnt_count(const int* __restrict__ ei, int* __restrict__ cnt, int E) {
    int i = blockIdx.x * blockDim.x + threadIdx.x;
    if (i < E) atomicAdd(&cnt[ei[E + i]], 1);
}

__global__ void dinv_from_cnt(const int* __restrict__ cnt, float* __restrict__ dinv, int n) {
    int i = blockIdx.x * blockDim.x + threadIdx.x;
    if (i < n) dinv[i] = rsqrtf((float)(cnt[i] + 1));
}

// single-block exclusive scan (n = 20000, chunked Hillis-Steele)
__global__ __launch_bounds__(1024) void scan_rowptr(const int* __restrict__ cnt,
                                                    int* __restrict__ rowptr, int n)
{
    __shared__ int sdata[1024];
    __shared__ int scarry;
    const int tid = threadIdx.x;
    if (tid == 0) scarry = 0;
    __syncthreads();
    for (int base = 0; base < n; base += 1024) {
        int i = base + tid;
        int v = (i < n) ? cnt[i] : 0;
        int x = v;
        sdata[tid] = x;
        __syncthreads();
#pragma unroll
        for (int off = 1; off < 1024; off <<= 1) {
            int y = (tid >= off) ? sdata[tid - off] : 0;
            __syncthreads();
            x += y;
            sdata[tid] = x;
            __syncthreads();
        }
        if (i < n) rowptr[i] = scarry + x - v;  // exclusive
        int total = sdata[1023];
        __syncthreads();
        if (tid == 0) scarry += total;
        __syncthreads();
    }
    if (tid == 0) rowptr[n] = scarry;
}

__global__ void csr_fill(const int* __restrict__ ei, const int* __restrict__ rowptr,
                         int* __restrict__ cursor, int* __restrict__ csr_src, int E)
{
    int e = blockIdx.x * blockDim.x + threadIdx.x;
    if (e < E) {
        int d = ei[E + e];
        int pos = rowptr[d] + atomicAdd(&cursor[d], 1);
        csr_src[pos] = ei[e];
    }
}

// ---------------------------------------------------------------------------
// fp32 -> bf16 cast (vectorized), and fp32 [R][C] -> bf16 [C][R] transpose
// ---------------------------------------------------------------------------
__global__ void cvt_bf16(const float4* __restrict__ in, ushort4* __restrict__ out, long long n4) {
    for (long long i = (long long)blockIdx.x * blockDim.x + threadIdx.x;
         i < n4; i += (long long)gridDim.x * blockDim.x) {
        float4 v = in[i];
        ushort4 o;
        o.x = f2bf(v.x); o.y = f2bf(v.y); o.z = f2bf(v.z); o.w = f2bf(v.w);
        out[i] = o;
    }
}

__global__ __launch_bounds__(256) void cvt_transpose_bf16(
    const float* __restrict__ in, bf16_t* __restrict__ out, int R, int C)
{
    __shared__ float tile[32][33];
    const int bx = blockIdx.x, by = blockIdx.y;   // bx over C/32, by over R/32
    const int tx = threadIdx.x & 31;
    const int ty = (threadIdx.x >> 5) * 4;
#pragma unroll
    for (int j = 0; j < 4; ++j)
        tile[ty + j][tx] = in[(long long)(by * 32 + ty + j) * C + bx * 32 + tx];
    __syncthreads();
#pragma unroll
    for (int j = 0; j < 4; ++j)
        out[(long long)(bx * 32 + ty + j) * R + by * 32 + tx] = f2bf(tile[tx][ty + j]);
}

#define GLOAD_LDS16(g, l)                                                     \
    __builtin_amdgcn_global_load_lds(                                         \
        (const __attribute__((address_space(1))) unsigned int*)(g),          \
        (__attribute__((address_space(3))) unsigned int*)(l), 16, 0, 0)

// ---------------------------------------------------------------------------
// 256x256 BF16 MFMA GEMM, BK=32 double-buffered (64 KiB LDS -> 2 blocks/CU,
// 4 waves/SIMD). r10 snake/park schedule, scaled to BK=32 (L=1 load/stage):
//   P1(0,0): rd A0,B0; stage (o).A1<-t+1
//   P2(1,0): rd A1 (B0 held); stage (o).B1<-t+1
//   P3(1,1): rd B1 (A1 held); stage (c).A0<-t+2
//   P4(0,1): rd none (A0 parked); stage (c).B0<-t+2; vmcnt(2)
// FIFO audit (1 load/stage): tile-start invariant = {t+1.A0,B0} outstanding;
// +4 during tile; vmcnt(2) drains the 4 oldest (t+1.*) leaving {t+2.A0,B0}.
// Swizzle (64 B rows, 4 x 16 B slots): slot ^= (row&3)^((row>>2)&3); on reads
// this is lane-constant (l&3)^((l>>2)&3); on the pre-swizzled global source
// it is (l&3)^((l>>2)&3)^((l>>4)&3). Same involution both sides (rule #21).
// Cross-block overlap (2 blocks/CU) covers barrier/vmcnt stalls that capped
// the 128 KiB variant at ~35% MfmaUtil (1 block/CU, nothing to co-schedule).
// ---------------------------------------------------------------------------
#define MFMA16(a, b, c) __builtin_amdgcn_mfma_f32_16x16x32_bf16((a), (b), (c), 0, 0, 0)

#define LDA_F(CUR, MH, MF)                                                    \
    (*(const bf16x8*)((const char*)(&lds[(CUR)][0][(MH)][0]) +                \
        (arow + (MF) * 16) * 64 + offk))
#define LDB_F(CUR, NH, NF)                                                    \
    (*(const bf16x8*)((const char*)(&lds[(CUR)][1][(NH)][0]) +                \
        (brw + (NF) * 16) * 64 + offk))

#define READ_AQ(DST, CUR, MH)                                                  \
    _Pragma("unroll")                                                          \
    for (int mf = 0; mf < 4; ++mf) { DST[mf] = LDA_F(CUR, MH, mf); }

#define READ_BQ(DST, CUR, NH)                                                  \
    _Pragma("unroll")                                                          \
    for (int nf = 0; nf < 2; ++nf) { DST[nf] = LDB_F(CUR, NH, nf); }

#define MFMA_Q(MH, NH, PA, PB)                                                 \
    do {                                                                       \
        __builtin_amdgcn_s_setprio(1);                                         \
        _Pragma("unroll")                                                      \
        for (int mf = 0; mf < 4; ++mf) {                                       \
            _Pragma("unroll")                                                  \
            for (int nf = 0; nf < 2; ++nf) {                                   \
                acc[MH][NH][mf][nf] = MFMA16(PA[mf], PB[nf], acc[MH][NH][mf][nf]); \
            }                                                                  \
        }                                                                      \
        __builtin_amdgcn_s_setprio(0);                                         \
    } while (0)

template <int HAS_BIAS, int RELU, int OUT_BF16>
__global__ __launch_bounds__(512, 4) void gemm_bf16_8ph(
    const bf16_t* __restrict__ A, const bf16_t* __restrict__ Bt,
    const float* __restrict__ bias, void* __restrict__ Cout,
    int M, int N, int K, int gx)
{
    __shared__ bf16_t lds[2][2][2][4096];   // [buf][A/B][half][128 rows x 32 k] = 64 KiB

    // bijective XCD chunk swizzle
    const int nwg = gridDim.x;
    const int q = nwg >> 3, r = nwg & 7;
    const int xcd = blockIdx.x & 7, lo = blockIdx.x >> 3;
    const int wgid = (xcd < r ? xcd * (q + 1) : r * (q + 1) + (xcd - r) * q) + lo;
    const int brow = (wgid / gx) * 256;
    const int bcol = (wgid % gx) * 256;

    const int tid = threadIdx.x;
    const int w = tid >> 6, l = tid & 63;
    const int wr = w >> 2, wc = w & 3;     // 2 x 4 wave grid
    const int nt = K >> 5;                 // BK=32 tiles

    f32x4 acc[2][2][4][2] = {};

    // staging lane constants: thread (w,l) writes LDS row w*16 + (l>>2),
    // phys slot l&3; source global k-slot is the swizzle involution.
    const int srowc = (w << 4) + (l >> 2);                         // 0..127
    const int sslot = (l & 3) ^ ((l >> 2) & 3) ^ ((l >> 4) & 3);   // src 16B slot

    auto stage_a = [&](int buf, int h, int s) {
        int grow = brow + h * 128 + srowc;
        if (grow > M - 1) grow = M - 1;           // clamp (in-bounds dup read)
        const bf16_t* g = A + (long long)grow * K + (s << 5) + sslot * 8;
        GLOAD_LDS16(g, &lds[buf][0][h][w * 512]);
    };
    auto stage_b = [&](int buf, int h, int s) {
        const int grow = bcol + h * 128 + srowc;   // N%256==0, no clamp
        const bf16_t* g = Bt + (long long)grow * K + (s << 5) + sslot * 8;
        GLOAD_LDS16(g, &lds[buf][1][h][w * 512]);
    };

    // ds_read address constants (read-side swizzle: same involution)
    const int arow = wr * 64 + (l & 15);
    const int brw  = wc * 32 + (l & 15);
    const int offk = ((((l >> 4) ^ (l & 3) ^ ((l >> 2) & 3)) & 3) << 4);  // byte in row

    // prologue: tile0 complete (4 loads) + tile1 A0,B0 (2 loads);
    // vmcnt(2) -> tile0 landed, tile1 A0,B0 in flight (steady-state invariant)
    stage_a(0, 0, 0); stage_b(0, 0, 0);
    stage_a(0, 1, 0); stage_b(0, 1, 0);
    stage_a(1, 0, 1); stage_b(1, 0, 1);
    __builtin_amdgcn_sched_barrier(0);
    asm volatile("s_waitcnt vmcnt(2)" ::: "memory");
    __builtin_amdgcn_sched_barrier(0);
    __builtin_amdgcn_s_barrier();

    int cur = 0;
    for (int t = 0; t < nt; ++t) {
        const int t1 = (t + 1 < nt) ? t + 1 : nt - 1;
        const int t2 = (t + 2 < nt) ? t + 2 : nt - 1;
        bf16x8 pa0[4], pa1[4], pb0[2], pb1[2];

        // P1 (0,0): read A0 (parked through P4) + B0; stage (o).A1 <- t+1
        __builtin_amdgcn_sched_barrier(0);
        READ_AQ(pa0, cur, 0);
        READ_BQ(pb0, cur, 0);
        stage_a(cur ^ 1, 1, t1);
        MFMA_Q(0, 0, pa0, pb0);
        __builtin_amdgcn_s_barrier();

        // P2 (1,0): read A1 (B0 held); stage (o).B1 <- t+1
        __builtin_amdgcn_sched_barrier(0);
        READ_AQ(pa1, cur, 1);
        stage_b(cur ^ 1, 1, t1);
        MFMA_Q(1, 0, pa1, pb0);
        __builtin_amdgcn_s_barrier();

        // P3 (1,1): read B1 (A1 held); stage (cur).A0 <- t+2 (last read t.P1)
        __builtin_amdgcn_sched_barrier(0);
        READ_BQ(pb1, cur, 1);
        stage_a(cur, 0, t2);
        MFMA_Q(1, 1, pa1, pb1);
        __builtin_amdgcn_s_barrier();

        // P4 (0,1): no reads (A0 parked, B1 held); stage (cur).B0 <- t+2
        __builtin_amdgcn_sched_barrier(0);
        stage_b(cur, 0, t2);
        MFMA_Q(0, 1, pa0, pb1);
        asm volatile("s_waitcnt vmcnt(2)" ::: "memory");
        __builtin_amdgcn_sched_barrier(0);
        __builtin_amdgcn_s_barrier();

        cur ^= 1;
    }

    // epilogue: C/D layout col=lane&15, row=(lane>>4)*4+j per 16x16 frag
#pragma unroll
    for (int mh = 0; mh < 2; ++mh) {
#pragma unroll
        for (int nh = 0; nh < 2; ++nh) {
#pragma unroll
            for (int nf = 0; nf < 2; ++nf) {
                const int col = bcol + nh * 128 + wc * 32 + nf * 16 + (l & 15);
                const float bv = HAS_BIAS ? bias[col] : 0.0f;
#pragma unroll
                for (int mf = 0; mf < 4; ++mf) {
#pragma unroll
                    for (int j = 0; j < 4; ++j) {
                        const int row = brow + mh * 128 + wr * 64 + mf * 16 + (l >> 4) * 4 + j;
                        if (row < M) {
                            float v = acc[mh][nh][mf][nf][j] + bv;
                            if (RELU) v = fmaxf(v, 0.0f);
                            if (OUT_BF16) ((bf16_t*)Cout)[(long long)row * N + col] = f2bf(v);
                            else          ((float*)Cout)[(long long)row * N + col] = v;
                        }
                    }
                }
            }
        }
    }
}

// ---------------------------------------------------------------------------
// m97-structure BF16 MFMA GEMM (kept for the two small GEMMs):
// C[M,N] = A[M,K] @ Bt[N,K]^T (+bias)(+relu), fp32 or bf16 out.
// ---------------------------------------------------------------------------
template <int HAS_BIAS, int RELU, int OUT_BF16, int BNT>
__global__ __launch_bounds__(256) void gemm_bf16_mfma(
    const bf16_t* __restrict__ A, const bf16_t* __restrict__ Bt,
    const float* __restrict__ bias, void* __restrict__ Cout,
    int M, int N, int K, int gx)
{
    constexpr int NFRAG = BNT / 32;
    constexpr int BHALF = BNT / 64;
    constexpr int WCOFF = BNT / 2;

    __shared__ bf16_t As[128 * 32];
    __shared__ bf16_t Bs[BNT * 32];

    const int nwg = gridDim.x;
    const int q = nwg >> 3, r = nwg & 7;
    const int xcd = blockIdx.x & 7, lo = blockIdx.x >> 3;
    const int wgid = (xcd < r ? xcd * (q + 1) : r * (q + 1) + (xcd - r) * q) + lo;
    const int brow = (wgid / gx) * 128;
    const int bcol = (wgid % gx) * BNT;

    const int tid = threadIdx.x;
    const int w   = tid >> 6;
    const int l   = tid & 63;
    const int wr  = w >> 1, wc = w & 1;

    f32x4 acc[4][NFRAG] = {};

    const int srow   = tid >> 2;
    const int schunk = (tid & 3) * 8;

    for (int k0 = 0; k0 < K; k0 += 32) {
#pragma unroll
        for (int half = 0; half < 2; ++half) {
            int gr = brow + half * 64 + srow;
            if (gr > M - 1) gr = M - 1;
            const bf16_t* gsrc = A + (long long)gr * K + k0 + schunk;
            GLOAD_LDS16(gsrc, &As[(half * 64 + w * 16) * 32]);
        }
#pragma unroll
        for (int half = 0; half < BHALF; ++half) {
            int rr = half * 64 + srow;
            const bf16_t* gsrc = Bt + (long long)(bcol + rr) * K + k0 + schunk;
            GLOAD_LDS16(gsrc, &Bs[(half * 64 + w * 16) * 32]);
        }
        __syncthreads();

        bf16x8 af[4], bfr[NFRAG];
#pragma unroll
        for (int m = 0; m < 4; ++m) {
            int row = wr * 64 + m * 16 + (l & 15);
            af[m] = *(const bf16x8*)&As[row * 32 + (l >> 4) * 8];
        }
#pragma unroll
        for (int n = 0; n < NFRAG; ++n) {
            int row = wc * WCOFF + n * 16 + (l & 15);
            bfr[n] = *(const bf16x8*)&Bs[row * 32 + (l >> 4) * 8];
        }
#pragma unroll
        for (int m = 0; m < 4; ++m)
#pragma unroll
            for (int n = 0; n < NFRAG; ++n)
                acc[m][n] = MFMA16(af[m], bfr[n], acc[m][n]);
        __syncthreads();
    }

#pragma unroll
    for (int m = 0; m < 4; ++m) {
#pragma unroll
        for (int n = 0; n < NFRAG; ++n) {
            int col = bcol + wc * WCOFF + n * 16 + (l & 15);
            float b = HAS_BIAS ? bias[col] : 0.0f;
#pragma unroll
            for (int j = 0; j < 4; ++j) {
                int row = brow + wr * 64 + m * 16 + (l >> 4) * 4 + j;
                if (row < M) {
                    float v = acc[m][n][j] + b;
                    if (RELU) v = fmaxf(v, 0.0f);
                    if (OUT_BF16) ((bf16_t*)Cout)[(long long)row * N + col] = f2bf(v);
                    else          ((float*)Cout)[(long long)row * N + col] = v;
                }
            }
        }
    }
}

// ---------------------------------------------------------------------------
// Fused GCN aggregation (CSR gather, bf16 h) + bias + ReLU + LN, F = 1536.
// One WAVE per dst row (4 rows/block); lane owns 3 bf16x8 chunks (24 feats).
// 2-edge ILP: two independent src-row load chains per iteration.
// ---------------------------------------------------------------------------
__global__ __launch_bounds__(256) void gcn_agg_ln_h(
    const bf16_t* __restrict__ h, const float* __restrict__ dinv,
    const int* __restrict__ rowptr, const int* __restrict__ csr_src,
    const float* __restrict__ bias, const float* __restrict__ g,
    const float* __restrict__ be, bf16_t* __restrict__ out, int n)
{
    const int row  = blockIdx.x * 4 + (threadIdx.x >> 6);
    const int lane = threadIdx.x & 63;
    if (row >= n) return;
    const float dd = dinv[row];

    float acc[24];
    {
        const bf16x8* hr = (const bf16x8*)(h + (long long)row * HH);
#pragma unroll
        for (int c = 0; c < 3; ++c) {
            bf16x8 v = hr[c * 64 + lane];
#pragma unroll
            for (int j = 0; j < 8; ++j) acc[c * 8 + j] = dd * (float)v[j];
        }
    }
    const int s0 = rowptr[row], s1 = rowptr[row + 1];
    int k = s0;
    for (; k + 1 < s1; k += 2) {
        const int sa = csr_src[k];
        const int sb = csr_src[k + 1];
        const float wa = dinv[sa];
        const float wb = dinv[sb];
        const bf16x8* ha = (const bf16x8*)(h + (long long)sa * HH);
        const bf16x8* hb = (const bf16x8*)(h + (long long)sb * HH);
        bf16x8 va[3], vb[3];
#pragma unroll
        for (int c = 0; c < 3; ++c) { va[c] = ha[c * 64 + lane]; vb[c] = hb[c * 64 + lane]; }
#pragma unroll
        for (int c = 0; c < 3; ++c)
#pragma unroll
            for (int j = 0; j < 8; ++j)
                acc[c * 8 + j] += wa * (float)va[c][j] + wb * (float)vb[c][j];
    }
    if (k < s1) {
        const int s = csr_src[k];
        const float wv = dinv[s];
        const bf16x8* hs = (const bf16x8*)(h + (long long)s * HH);
#pragma unroll
        for (int c = 0; c < 3; ++c) {
            bf16x8 v = hs[c * 64 + lane];
#pragma unroll
            for (int j = 0; j < 8; ++j) acc[c * 8 + j] += wv * (float)v[j];
        }
    }

    float lsum = 0.0f, lsq = 0.0f;
#pragma unroll
    for (int c = 0; c < 3; ++c)
#pragma unroll
        for (int j = 0; j < 8; ++j) {
            int idx = c * 512 + lane * 8 + j;
            float v = fmaxf(acc[c * 8 + j] * dd + bias[idx], 0.0f);
            acc[c * 8 + j] = v;
            lsum += v;
            lsq  += v * v;
        }
#pragma unroll
    for (int off = 32; off > 0; off >>= 1) {
        lsum += __shfl_xor(lsum, off);
        lsq  += __shfl_xor(lsq,  off);
    }
    const float mean = lsum / HH;
    const float var  = lsq / HH - mean * mean;
    const float rstd = rsqrtf(var + 1e-5f);

    bf16_t* y = out + (long long)row * HH;
#pragma unroll
    for (int c = 0; c < 3; ++c)
#pragma unroll
        for (int j = 0; j < 8; ++j) {
            int idx = c * 512 + lane * 8 + j;
            y[idx] = f2bf((acc[c * 8 + j] - mean) * rstd * g[idx] + be[idx]);
        }
}

// Same, F = 64 (fp32 h): writes fp32 latent (output 0) AND bf16 copy.
__global__ __launch_bounds__(256) void gcn_agg_ln_l(
    const float* __restrict__ h, const float* __restrict__ dinv,
    const int* __restrict__ rowptr, const int* __restrict__ csr_src,
    const float* __restrict__ bias, const float* __restrict__ g,
    const float* __restrict__ be, float* __restrict__ out,
    bf16_t* __restrict__ outb, int n)
{
    const int row  = blockIdx.x * 4 + (threadIdx.x >> 6);
    const int lane = threadIdx.x & 63;
    if (row >= n) return;
    const float dd = dinv[row];

    float acc = dd * h[(long long)row * LL + lane];
    const int s0 = rowptr[row], s1 = rowptr[row + 1];
    for (int k = s0; k < s1; ++k) {
        const int s = csr_src[k];
        acc += dinv[s] * h[(long long)s * LL + lane];
    }
    float v = fmaxf(acc * dd + bias[lane], 0.0f);
    float lsum = v, lsq = v * v;
#pragma unroll
    for (int off = 32; off > 0; off >>= 1) {
        lsum += __shfl_xor(lsum, off);
        lsq  += __shfl_xor(lsq,  off);
    }
    const float mean = lsum / LL;
    const float var  = lsq / LL - mean * mean;
    const float rstd = rsqrtf(var + 1e-5f);
    float o = (v - mean) * rstd * g[lane] + be[lane];
    out[(long long)row * LL + lane]  = o;
    outb[(long long)row * LL + lane] = f2bf(o);
}

// ---------------------------------------------------------------------------
// Launch.
// ---------------------------------------------------------------------------
extern "C" void kernel_launch(void* const* d_in, const int* in_sizes, int n_in,
                              void* d_out, int out_size, void* d_ws, size_t ws_size,
                              hipStream_t stream)
{
    const float* x     = (const float*)d_in[0];
    const int*   ei    = (const int*)d_in[1];
    const float* W_gc1 = (const float*)d_in[2];
    const float* b_gc1 = (const float*)d_in[3];
    const float* W_gc2 = (const float*)d_in[4];
    const float* b_gc2 = (const float*)d_in[5];
    const float* g1    = (const float*)d_in[6];
    const float* be1   = (const float*)d_in[7];
    const float* g2    = (const float*)d_in[8];
    const float* be2   = (const float*)d_in[9];
    const float* W_fc1 = (const float*)d_in[10];
    const float* b_fc1 = (const float*)d_in[11];
    const float* W_fc2 = (const float*)d_in[12];
    const float* b_fc2 = (const float*)d_in[13];

    float* out_latent = (float*)d_out;                       // [N, L]
    float* out_recon  = (float*)d_out + (long long)NN * LL;  // [N, D]

    bf16_t* h1b     = (bf16_t*)out_recon;                         // N*H bf16
    bf16_t* hiddenb = (bf16_t*)(out_recon + (long long)NN * HH);  // N*H bf16 (2nd half)

    float*  dinv    = (float*)d_ws;                          // N
    int*    cnt     = (int*)(dinv + NN);                     // N
    int*    cursor  = cnt + NN;                              // N
    int*    rowptr  = cursor + NN;                           // N+1
    int*    csr_src = rowptr + NN + 1;                       // E
    char*   pbase   = (char*)(csr_src + EE);
    pbase = (char*)(((size_t)pbase + 255) & ~(size_t)255);
    bf16_t* xb      = (bf16_t*)pbase;                        // N*D bf16 (later decodeb)
    bf16_t* W1t     = xb + (long long)NN * DD;               // H*D bf16 (W_gc1^T)
    bf16_t* W2t     = W1t + (long long)DD * HH;              // D*H bf16 (W_fc2^T)
    bf16_t* Wg2t    = W2t + (long long)DD * HH;              // L*H bf16 (W_gc2^T)
    bf16_t* Wf1t    = Wg2t + (long long)HH * LL;             // H*L bf16 (W_fc1^T)
    bf16_t* latentb = Wf1t + (long long)LL * HH;             // N*L bf16
    float*  wsC     = (float*)(latentb + (long long)NN * LL); // N*L f32 (h2)
    bf16_t* decodeb = xb;                                    // N*H bf16, reuses xb

    // 1) CSR build + dinv
    zero_int<<<(2 * NN + 255) / 256, 256, 0, stream>>>(cnt, 2 * NN);
    cnt_count<<<(EE + 255) / 256, 256, 0, stream>>>(ei, cnt, EE);
    dinv_from_cnt<<<(NN + 255) / 256, 256, 0, stream>>>(cnt, dinv, NN);
    scan_rowptr<<<1, 1024, 0, stream>>>(cnt, rowptr, NN);
    csr_fill<<<(EE + 255) / 256, 256, 0, stream>>>(ei, rowptr, cursor, csr_src, EE);

    // 2) bf16 conversions
    cvt_bf16<<<2048, 256, 0, stream>>>((const float4*)x, (ushort4*)xb, (long long)NN * DD / 4);
    {
        dim3 ga(HH / 32, DD / 32);
        cvt_transpose_bf16<<<ga, 256, 0, stream>>>(W_gc1, W1t, DD, HH);
        dim3 gb(DD / 32, HH / 32);
        cvt_transpose_bf16<<<gb, 256, 0, stream>>>(W_fc2, W2t, HH, DD);
        dim3 gc(LL / 32, HH / 32);
        cvt_transpose_bf16<<<gc, 256, 0, stream>>>(W_gc2, Wg2t, HH, LL);
        dim3 gd(HH / 32, LL / 32);
        cvt_transpose_bf16<<<gd, 256, 0, stream>>>(W_fc1, Wf1t, LL, HH);
    }

    const int MB128 = (NN + 127) / 128;   // 157
    const int MB256 = (NN + 255) / 256;   // 79

    // 3) h1b = bf16(xb @ W1t^T)   [N, H]   (256x256, BK=32, 2 blocks/CU)
    {
        int gx = HH / 256;   // 6
        gemm_bf16_8ph<0, 0, 1><<<gx * MB256, 512, 0, stream>>>(xb, W1t, nullptr, h1b, NN, HH, DD, gx);
    }

    // 4) hiddenb = bf16(LN(relu(agg(h1b) + b_gc1)))
    gcn_agg_ln_h<<<(NN + 3) / 4, 256, 0, stream>>>(h1b, dinv, rowptr, csr_src, b_gc1, g1, be1, hiddenb, NN);

    // 5) h2 = hiddenb @ Wg2t^T    [N, L] f32 -> wsC   (MFMA 128x64)
    gemm_bf16_mfma<0, 0, 0, 64><<<MB128, 256, 0, stream>>>(hiddenb, Wg2t, nullptr, wsC, NN, LL, HH, 1);

    // 6) latent = LN(relu(agg(h2) + b_gc2)) -> output 0 (+ bf16 copy)
    gcn_agg_ln_l<<<(NN + 3) / 4, 256, 0, stream>>>(wsC, dinv, rowptr, csr_src, b_gc2, g2, be2, out_latent, latentb, NN);

    // 7) decodeb = bf16(relu(latentb @ Wf1t^T + b_fc1))  [N, H] (MFMA 128x128, K=64)
    {
        int gx = HH / 128;
        gemm_bf16_mfma<1, 1, 1, 128><<<gx * MB128, 256, 0, stream>>>(latentb, Wf1t, b_fc1, decodeb, NN, HH, LL, gx);
    }

    // 8) reconstructed = decodeb @ W2t^T + b_fc2  [N, D] -> output 1 (BK=32)
    {
        int gx = DD / 256;   // 12
        gemm_bf16_8ph<1, 0, 0><<<gx * MB256, 512, 0, stream>>>(decodeb, W2t, b_fc2, out_recon, NN, DD, HH, gx);
    }
}

// Round 15
// 782.105 us; speedup vs baseline: 4.7896x; 4.7896x over previous
//
#include <hip/hip_runtime.h>
#include <hip/hip_bf16.h>

// Problem constants (match reference)
#define NN 20000
#define EE 320000
#define DD 3072
#define HH 1536
#define LL 64

typedef unsigned short bf16_t;
typedef __attribute__((ext_vector_type(8))) __bf16 bf16x8;
typedef __attribute__((ext_vector_type(4))) float  f32x4;

__device__ __forceinline__ bf16_t f2bf(float f) {
    union { float f; unsigned u; } c; c.f = f;
    unsigned u = c.u;
    return (bf16_t)((u + 0x7fffu + ((u >> 16) & 1u)) >> 16);  // RNE (inputs finite)
}

// ---------------------------------------------------------------------------
// CSR build. edge_index is int32: src = ei[e], dst = ei[E+e].
// ---------------------------------------------------------------------------
__global__ void zero_int(int* __restrict__ p, int n) {
    int i = blockIdx.x * blockDim.x + threadIdx.x;
    if (i < n) p[i] = 0;
}

__global__ void cnt_count(const int* __restrict__ ei, int* __restrict__ cnt, int E) {
    int i = blockIdx.x * blockDim.x + threadIdx.x;
    if (i < E) atomicAdd(&cnt[ei[E + i]], 1);
}

__global__ void dinv_from_cnt(const int* __restrict__ cnt, float* __restrict__ dinv, int n) {
    int i = blockIdx.x * blockDim.x + threadIdx.x;
    if (i < n) dinv[i] = rsqrtf((float)(cnt[i] + 1));
}

// single-block exclusive scan (n = 20000, chunked Hillis-Steele)
__global__ __launch_bounds__(1024) void scan_rowptr(const int* __restrict__ cnt,
                                                    int* __restrict__ rowptr, int n)
{
    __shared__ int sdata[1024];
    __shared__ int scarry;
    const int tid = threadIdx.x;
    if (tid == 0) scarry = 0;
    __syncthreads();
    for (int base = 0; base < n; base += 1024) {
        int i = base + tid;
        int v = (i < n) ? cnt[i] : 0;
        int x = v;
        sdata[tid] = x;
        __syncthreads();
#pragma unroll
        for (int off = 1; off < 1024; off <<= 1) {
            int y = (tid >= off) ? sdata[tid - off] : 0;
            __syncthreads();
            x += y;
            sdata[tid] = x;
            __syncthreads();
        }
        if (i < n) rowptr[i] = scarry + x - v;  // exclusive
        int total = sdata[1023];
        __syncthreads();
        if (tid == 0) scarry += total;
        __syncthreads();
    }
    if (tid == 0) rowptr[n] = scarry;
}

__global__ void csr_fill(const int* __restrict__ ei, const int* __restrict__ rowptr,
                         int* __restrict__ cursor, int* __restrict__ csr_src, int E)
{
    int e = blockIdx.x * blockDim.x + threadIdx.x;
    if (e < E) {
        int d = ei[E + e];
        int pos = rowptr[d] + atomicAdd(&cursor[d], 1);
        csr_src[pos] = ei[e];
    }
}

// ---------------------------------------------------------------------------
// fp32 -> bf16 cast (vectorized), and fp32 [R][C] -> bf16 [C][R] transpose
// ---------------------------------------------------------------------------
__global__ void cvt_bf16(const float4* __restrict__ in, ushort4* __restrict__ out, long long n4) {
    for (long long i = (long long)blockIdx.x * blockDim.x + threadIdx.x;
         i < n4; i += (long long)gridDim.x * blockDim.x) {
        float4 v = in[i];
        ushort4 o;
        o.x = f2bf(v.x); o.y = f2bf(v.y); o.z = f2bf(v.z); o.w = f2bf(v.w);
        out[i] = o;
    }
}

__global__ __launch_bounds__(256) void cvt_transpose_bf16(
    const float* __restrict__ in, bf16_t* __restrict__ out, int R, int C)
{
    __shared__ float tile[32][33];
    const int bx = blockIdx.x, by = blockIdx.y;   // bx over C/32, by over R/32
    const int tx = threadIdx.x & 31;
    const int ty = (threadIdx.x >> 5) * 4;
#pragma unroll
    for (int j = 0; j < 4; ++j)
        tile[ty + j][tx] = in[(long long)(by * 32 + ty + j) * C + bx * 32 + tx];
    __syncthreads();
#pragma unroll
    for (int j = 0; j < 4; ++j)
        out[(long long)(bx * 32 + ty + j) * R + by * 32 + tx] = f2bf(tile[tx][ty + j]);
}

#define GLOAD_LDS16(g, l)                                                     \
    __builtin_amdgcn_global_load_lds(                                         \
        (const __attribute__((address_space(1))) unsigned int*)(g),          \
        (__attribute__((address_space(3))) unsigned int*)(l), 16, 0, 0)

// ---------------------------------------------------------------------------
// 256x256 BF16 MFMA GEMM, BK=64 double-buffer (128 KiB LDS), 4 phases/tile,
// snake order, ONE-PHASE-AHEAD register prefetch (r11 best-measured: 233 us,
// MfmaUtil ~35.5%). Reads/tile/wave = 20,4,0,0 = 24 (minimum).
//   P1(0,0): rd A0,B0 + prefetch A1; stage (o).A1<-t+1
//   P2(1,0): prefetch B1;            stage (o).B1<-t+1
//   P3(1,1): no reads;               stage (c).A0<-t+2
//   P4(0,1): no reads;               stage (c).B0<-t+2; vmcnt(4)
// Validity: (c).A1/(c).B1 staged at t-1.P1/P2 are within the first-4 loads
// drained by t-1's vmcnt(4) -> landed before tile t begins (induction
// anchored by the prologue). Stage targets >= 2 barriers after last read.
// NOTE (r14 lesson): acc alone = 128 VGPR/lane at this tile -> 2 waves/SIMD
// is the occupancy ceiling; do NOT force higher via __launch_bounds__
// (forces spill cascade: VGPR=64, FETCH 16x, MfmaUtil 4.5%).
// ---------------------------------------------------------------------------
#define MFMA16(a, b, c) __builtin_amdgcn_mfma_f32_16x16x32_bf16((a), (b), (c), 0, 0, 0)

#define LDA_F(CUR, MH, MF, KS)                                                \
    (*(const bf16x8*)((const char*)(&lds[(CUR)][0][(MH)][0]) +                \
        (arow + (MF) * 16) * 128 + ((KS) ? offk1 : offk0)))
#define LDB_F(CUR, NH, NF, KS)                                                \
    (*(const bf16x8*)((const char*)(&lds[(CUR)][1][(NH)][0]) +                \
        (brw + (NF) * 16) * 128 + ((KS) ? offk1 : offk0)))

#define READ_AQ(DST, CUR, MH)                                                  \
    _Pragma("unroll")                                                          \
    for (int mf = 0; mf < 4; ++mf) {                                           \
        DST[mf][0] = LDA_F(CUR, MH, mf, 0);                                    \
        DST[mf][1] = LDA_F(CUR, MH, mf, 1);                                    \
    }

#define READ_BQ(DST, CUR, NH)                                                  \
    _Pragma("unroll")                                                          \
    for (int nf = 0; nf < 2; ++nf) {                                           \
        DST[nf][0] = LDB_F(CUR, NH, nf, 0);                                    \
        DST[nf][1] = LDB_F(CUR, NH, nf, 1);                                    \
    }

#define MFMA_Q(MH, NH, PA, PB)                                                 \
    do {                                                                       \
        __builtin_amdgcn_s_setprio(1);                                         \
        _Pragma("unroll")                                                      \
        for (int mf = 0; mf < 4; ++mf) {                                       \
            _Pragma("unroll")                                                  \
            for (int nf = 0; nf < 2; ++nf) {                                   \
                acc[MH][NH][mf][nf] = MFMA16(PA[mf][0], PB[nf][0], acc[MH][NH][mf][nf]); \
                acc[MH][NH][mf][nf] = MFMA16(PA[mf][1], PB[nf][1], acc[MH][NH][mf][nf]); \
            }                                                                  \
        }                                                                      \
        __builtin_amdgcn_s_setprio(0);                                         \
    } while (0)

template <int HAS_BIAS, int RELU, int OUT_BF16>
__global__ __launch_bounds__(512, 2) void gemm_bf16_8ph(
    const bf16_t* __restrict__ A, const bf16_t* __restrict__ Bt,
    const float* __restrict__ bias, void* __restrict__ Cout,
    int M, int N, int K, int gx)
{
    __shared__ bf16_t lds[2][2][2][8192];   // [buf][A/B][half][128 rows x 64 k] = 128 KiB

    // bijective XCD chunk swizzle
    const int nwg = gridDim.x;
    const int q = nwg >> 3, r = nwg & 7;
    const int xcd = blockIdx.x & 7, lo = blockIdx.x >> 3;
    const int wgid = (xcd < r ? xcd * (q + 1) : r * (q + 1) + (xcd - r) * q) + lo;
    const int brow = (wgid / gx) * 256;
    const int bcol = (wgid % gx) * 256;

    const int tid = threadIdx.x;
    const int w = tid >> 6, l = tid & 63;
    const int wr = w >> 2, wc = w & 3;     // 2 x 4 wave grid
    const int nt = K >> 6;                 // BK=64 tiles

    f32x4 acc[2][2][4][2] = {};

    // staging lane constants: chunk c = w*2+i covers rows c*8..c*8+7 (1 KiB)
    const int srow8 = l >> 3;                         // row within chunk
    const int swz8  = (((l & 7) ^ (l >> 3)) << 3);    // swizzled k-slot (bf16 units)

    auto stage_a = [&](int buf, int h, int s) {
#pragma unroll
        for (int i = 0; i < 2; ++i) {
            const int c = (w << 1) + i;
            int grow = brow + h * 128 + c * 8 + srow8;
            if (grow > M - 1) grow = M - 1;           // clamp (in-bounds dup read)
            const bf16_t* g = A + (long long)grow * K + (s << 6) + swz8;
            GLOAD_LDS16(g, &lds[buf][0][h][c * 512]);
        }
    };
    auto stage_b = [&](int buf, int h, int s) {
#pragma unroll
        for (int i = 0; i < 2; ++i) {
            const int c = (w << 1) + i;
            const int grow = bcol + h * 128 + c * 8 + srow8;   // N%256==0, no clamp
            const bf16_t* g = Bt + (long long)grow * K + (s << 6) + swz8;
            GLOAD_LDS16(g, &lds[buf][1][h][c * 512]);
        }
    };

    // ds_read address constants (read-side swizzle: same involution)
    const int arow  = wr * 64 + (l & 15);
    const int brw   = wc * 32 + (l & 15);
    const int xm    = (l & 7) << 4;
    const int offk0 = ((l >> 4) << 4) ^ xm;
    const int offk1 = (((l >> 4) << 4) + 64) ^ xm;

    // prologue: tile0 complete (8 loads) + tile1 A0,B0 (4 loads);
    // vmcnt(4) -> tile0 landed, tile1 A0,B0 in flight (steady-state invariant)
    stage_a(0, 0, 0); stage_b(0, 0, 0);
    stage_a(0, 1, 0); stage_b(0, 1, 0);
    stage_a(1, 0, 1); stage_b(1, 0, 1);
    __builtin_amdgcn_sched_barrier(0);
    asm volatile("s_waitcnt vmcnt(4)" ::: "memory");
    __builtin_amdgcn_sched_barrier(0);
    __builtin_amdgcn_s_barrier();

    int cur = 0;
    for (int t = 0; t < nt; ++t) {
        const int t1 = (t + 1 < nt) ? t + 1 : nt - 1;
        const int t2 = (t + 2 < nt) ? t + 2 : nt - 1;
        bf16x8 pa0[4][2], pa1[4][2], pb0[2][2], pb1[2][2];

        // P1 (0,0): read A0+B0 (own) + prefetch A1; stage (o).A1 <- t+1
        __builtin_amdgcn_sched_barrier(0);
        READ_AQ(pa0, cur, 0);
        READ_BQ(pb0, cur, 0);
        READ_AQ(pa1, cur, 1);              // prefetch for P2 (valid since t-1)
        stage_a(cur ^ 1, 1, t1);
        MFMA_Q(0, 0, pa0, pb0);
        __builtin_amdgcn_s_barrier();

        // P2 (1,0): prefetch B1 for P3; stage (o).B1 <- t+1
        __builtin_amdgcn_sched_barrier(0);
        READ_BQ(pb1, cur, 1);              // prefetch for P3 (valid since t-1)
        stage_b(cur ^ 1, 1, t1);
        MFMA_Q(1, 0, pa1, pb0);
        __builtin_amdgcn_s_barrier();

        // P3 (1,1): no reads; stage (cur).A0 <- t+2 (last read of A0 was t.P1)
        __builtin_amdgcn_sched_barrier(0);
        stage_a(cur, 0, t2);
        MFMA_Q(1, 1, pa1, pb1);
        __builtin_amdgcn_s_barrier();

        // P4 (0,1): no reads; stage (cur).B0 <- t+2; counted vmcnt
        __builtin_amdgcn_sched_barrier(0);
        stage_b(cur, 0, t2);
        MFMA_Q(0, 1, pa0, pb1);
        asm volatile("s_waitcnt vmcnt(4)" ::: "memory");
        __builtin_amdgcn_sched_barrier(0);
        __builtin_amdgcn_s_barrier();

        cur ^= 1;
    }

    // epilogue: C/D layout col=lane&15, row=(lane>>4)*4+j per 16x16 frag
#pragma unroll
    for (int mh = 0; mh < 2; ++mh) {
#pragma unroll
        for (int nh = 0; nh < 2; ++nh) {
#pragma unroll
            for (int nf = 0; nf < 2; ++nf) {
                const int col = bcol + nh * 128 + wc * 32 + nf * 16 + (l & 15);
                const float bv = HAS_BIAS ? bias[col] : 0.0f;
#pragma unroll
                for (int mf = 0; mf < 4; ++mf) {
#pragma unroll
                    for (int j = 0; j < 4; ++j) {
                        const int row = brow + mh * 128 + wr * 64 + mf * 16 + (l >> 4) * 4 + j;
                        if (row < M) {
                            float v = acc[mh][nh][mf][nf][j] + bv;
                            if (RELU) v = fmaxf(v, 0.0f);
                            if (OUT_BF16) ((bf16_t*)Cout)[(long long)row * N + col] = f2bf(v);
                            else          ((float*)Cout)[(long long)row * N + col] = v;
                        }
                    }
                }
            }
        }
    }
}

// ---------------------------------------------------------------------------
// m97-structure BF16 MFMA GEMM (kept for the two small GEMMs):
// C[M,N] = A[M,K] @ Bt[N,K]^T (+bias)(+relu), fp32 or bf16 out.
// ---------------------------------------------------------------------------
template <int HAS_BIAS, int RELU, int OUT_BF16, int BNT>
__global__ __launch_bounds__(256) void gemm_bf16_mfma(
    const bf16_t* __restrict__ A, const bf16_t* __restrict__ Bt,
    const float* __restrict__ bias, void* __restrict__ Cout,
    int M, int N, int K, int gx)
{
    constexpr int NFRAG = BNT / 32;
    constexpr int BHALF = BNT / 64;
    constexpr int WCOFF = BNT / 2;

    __shared__ bf16_t As[128 * 32];
    __shared__ bf16_t Bs[BNT * 32];

    const int nwg = gridDim.x;
    const int q = nwg >> 3, r = nwg & 7;
    const int xcd = blockIdx.x & 7, lo = blockIdx.x >> 3;
    const int wgid = (xcd < r ? xcd * (q + 1) : r * (q + 1) + (xcd - r) * q) + lo;
    const int brow = (wgid / gx) * 128;
    const int bcol = (wgid % gx) * BNT;

    const int tid = threadIdx.x;
    const int w   = tid >> 6;
    const int l   = tid & 63;
    const int wr  = w >> 1, wc = w & 1;

    f32x4 acc[4][NFRAG] = {};

    const int srow   = tid >> 2;
    const int schunk = (tid & 3) * 8;

    for (int k0 = 0; k0 < K; k0 += 32) {
#pragma unroll
        for (int half = 0; half < 2; ++half) {
            int gr = brow + half * 64 + srow;
            if (gr > M - 1) gr = M - 1;
            const bf16_t* gsrc = A + (long long)gr * K + k0 + schunk;
            GLOAD_LDS16(gsrc, &As[(half * 64 + w * 16) * 32]);
        }
#pragma unroll
        for (int half = 0; half < BHALF; ++half) {
            int rr = half * 64 + srow;
            const bf16_t* gsrc = Bt + (long long)(bcol + rr) * K + k0 + schunk;
            GLOAD_LDS16(gsrc, &Bs[(half * 64 + w * 16) * 32]);
        }
        __syncthreads();

        bf16x8 af[4], bfr[NFRAG];
#pragma unroll
        for (int m = 0; m < 4; ++m) {
            int row = wr * 64 + m * 16 + (l & 15);
            af[m] = *(const bf16x8*)&As[row * 32 + (l >> 4) * 8];
        }
#pragma unroll
        for (int n = 0; n < NFRAG; ++n) {
            int row = wc * WCOFF + n * 16 + (l & 15);
            bfr[n] = *(const bf16x8*)&Bs[row * 32 + (l >> 4) * 8];
        }
#pragma unroll
        for (int m = 0; m < 4; ++m)
#pragma unroll
            for (int n = 0; n < NFRAG; ++n)
                acc[m][n] = MFMA16(af[m], bfr[n], acc[m][n]);
        __syncthreads();
    }

#pragma unroll
    for (int m = 0; m < 4; ++m) {
#pragma unroll
        for (int n = 0; n < NFRAG; ++n) {
            int col = bcol + wc * WCOFF + n * 16 + (l & 15);
            float b = HAS_BIAS ? bias[col] : 0.0f;
#pragma unroll
            for (int j = 0; j < 4; ++j) {
                int row = brow + wr * 64 + m * 16 + (l >> 4) * 4 + j;
                if (row < M) {
                    float v = acc[m][n][j] + b;
                    if (RELU) v = fmaxf(v, 0.0f);
                    if (OUT_BF16) ((bf16_t*)Cout)[(long long)row * N + col] = f2bf(v);
                    else          ((float*)Cout)[(long long)row * N + col] = v;
                }
            }
        }
    }
}

// ---------------------------------------------------------------------------
// Fused GCN aggregation (CSR gather, bf16 h) + bias + ReLU + LN, F = 1536.
// One WAVE per dst row (4 rows/block); lane owns 3 bf16x8 chunks (24 feats).
// 2-edge ILP: two independent src-row load chains per iteration.
// ---------------------------------------------------------------------------
__global__ __launch_bounds__(256) void gcn_agg_ln_h(
    const bf16_t* __restrict__ h, const float* __restrict__ dinv,
    const int* __restrict__ rowptr, const int* __restrict__ csr_src,
    const float* __restrict__ bias, const float* __restrict__ g,
    const float* __restrict__ be, bf16_t* __restrict__ out, int n)
{
    const int row  = blockIdx.x * 4 + (threadIdx.x >> 6);
    const int lane = threadIdx.x & 63;
    if (row >= n) return;
    const float dd = dinv[row];

    float acc[24];
    {
        const bf16x8* hr = (const bf16x8*)(h + (long long)row * HH);
#pragma unroll
        for (int c = 0; c < 3; ++c) {
            bf16x8 v = hr[c * 64 + lane];
#pragma unroll
            for (int j = 0; j < 8; ++j) acc[c * 8 + j] = dd * (float)v[j];
        }
    }
    const int s0 = rowptr[row], s1 = rowptr[row + 1];
    int k = s0;
    for (; k + 1 < s1; k += 2) {
        const int sa = csr_src[k];
        const int sb = csr_src[k + 1];
        const float wa = dinv[sa];
        const float wb = dinv[sb];
        const bf16x8* ha = (const bf16x8*)(h + (long long)sa * HH);
        const bf16x8* hb = (const bf16x8*)(h + (long long)sb * HH);
        bf16x8 va[3], vb[3];
#pragma unroll
        for (int c = 0; c < 3; ++c) { va[c] = ha[c * 64 + lane]; vb[c] = hb[c * 64 + lane]; }
#pragma unroll
        for (int c = 0; c < 3; ++c)
#pragma unroll
            for (int j = 0; j < 8; ++j)
                acc[c * 8 + j] += wa * (float)va[c][j] + wb * (float)vb[c][j];
    }
    if (k < s1) {
        const int s = csr_src[k];
        const float wv = dinv[s];
        const bf16x8* hs = (const bf16x8*)(h + (long long)s * HH);
#pragma unroll
        for (int c = 0; c < 3; ++c) {
            bf16x8 v = hs[c * 64 + lane];
#pragma unroll
            for (int j = 0; j < 8; ++j) acc[c * 8 + j] += wv * (float)v[j];
        }
    }

    float lsum = 0.0f, lsq = 0.0f;
#pragma unroll
    for (int c = 0; c < 3; ++c)
#pragma unroll
        for (int j = 0; j < 8; ++j) {
            int idx = c * 512 + lane * 8 + j;
            float v = fmaxf(acc[c * 8 + j] * dd + bias[idx], 0.0f);
            acc[c * 8 + j] = v;
            lsum += v;
            lsq  += v * v;
        }
#pragma unroll
    for (int off = 32; off > 0; off >>= 1) {
        lsum += __shfl_xor(lsum, off);
        lsq  += __shfl_xor(lsq,  off);
    }
    const float mean = lsum / HH;
    const float var  = lsq / HH - mean * mean;
    const float rstd = rsqrtf(var + 1e-5f);

    bf16_t* y = out + (long long)row * HH;
#pragma unroll
    for (int c = 0; c < 3; ++c)
#pragma unroll
        for (int j = 0; j < 8; ++j) {
            int idx = c * 512 + lane * 8 + j;
            y[idx] = f2bf((acc[c * 8 + j] - mean) * rstd * g[idx] + be[idx]);
        }
}

// Same, F = 64 (fp32 h): writes fp32 latent (output 0) AND bf16 copy.
__global__ __launch_bounds__(256) void gcn_agg_ln_l(
    const float* __restrict__ h, const float* __restrict__ dinv,
    const int* __restrict__ rowptr, const int* __restrict__ csr_src,
    const float* __restrict__ bias, const float* __restrict__ g,
    const float* __restrict__ be, float* __restrict__ out,
    bf16_t* __restrict__ outb, int n)
{
    const int row  = blockIdx.x * 4 + (threadIdx.x >> 6);
    const int lane = threadIdx.x & 63;
    if (row >= n) return;
    const float dd = dinv[row];

    float acc = dd * h[(long long)row * LL + lane];
    const int s0 = rowptr[row], s1 = rowptr[row + 1];
    for (int k = s0; k < s1; ++k) {
        const int s = csr_src[k];
        acc += dinv[s] * h[(long long)s * LL + lane];
    }
    float v = fmaxf(acc * dd + bias[lane], 0.0f);
    float lsum = v, lsq = v * v;
#pragma unroll
    for (int off = 32; off > 0; off >>= 1) {
        lsum += __shfl_xor(lsum, off);
        lsq  += __shfl_xor(lsq,  off);
    }
    const float mean = lsum / LL;
    const float var  = lsq / LL - mean * mean;
    const float rstd = rsqrtf(var + 1e-5f);
    float o = (v - mean) * rstd * g[lane] + be[lane];
    out[(long long)row * LL + lane]  = o;
    outb[(long long)row * LL + lane] = f2bf(o);
}

// ---------------------------------------------------------------------------
// Launch.
// ---------------------------------------------------------------------------
extern "C" void kernel_launch(void* const* d_in, const int* in_sizes, int n_in,
                              void* d_out, int out_size, void* d_ws, size_t ws_size,
                              hipStream_t stream)
{
    const float* x     = (const float*)d_in[0];
    const int*   ei    = (const int*)d_in[1];
    const float* W_gc1 = (const float*)d_in[2];
    const float* b_gc1 = (const float*)d_in[3];
    const float* W_gc2 = (const float*)d_in[4];
    const float* b_gc2 = (const float*)d_in[5];
    const float* g1    = (const float*)d_in[6];
    const float* be1   = (const float*)d_in[7];
    const float* g2    = (const float*)d_in[8];
    const float* be2   = (const float*)d_in[9];
    const float* W_fc1 = (const float*)d_in[10];
    const float* b_fc1 = (const float*)d_in[11];
    const float* W_fc2 = (const float*)d_in[12];
    const float* b_fc2 = (const float*)d_in[13];

    float* out_latent = (float*)d_out;                       // [N, L]
    float* out_recon  = (float*)d_out + (long long)NN * LL;  // [N, D]

    bf16_t* h1b     = (bf16_t*)out_recon;                         // N*H bf16
    bf16_t* hiddenb = (bf16_t*)(out_recon + (long long)NN * HH);  // N*H bf16 (2nd half)

    float*  dinv    = (float*)d_ws;                          // N
    int*    cnt     = (int*)(dinv + NN);                     // N
    int*    cursor  = cnt + NN;                              // N
    int*    rowptr  = cursor + NN;                           // N+1
    int*    csr_src = rowptr + NN + 1;                       // E
    char*   pbase   = (char*)(csr_src + EE);
    pbase = (char*)(((size_t)pbase + 255) & ~(size_t)255);
    bf16_t* xb      = (bf16_t*)pbase;                        // N*D bf16 (later decodeb)
    bf16_t* W1t     = xb + (long long)NN * DD;               // H*D bf16 (W_gc1^T)
    bf16_t* W2t     = W1t + (long long)DD * HH;              // D*H bf16 (W_fc2^T)
    bf16_t* Wg2t    = W2t + (long long)DD * HH;              // L*H bf16 (W_gc2^T)
    bf16_t* Wf1t    = Wg2t + (long long)HH * LL;             // H*L bf16 (W_fc1^T)
    bf16_t* latentb = Wf1t + (long long)LL * HH;             // N*L bf16
    float*  wsC     = (float*)(latentb + (long long)NN * LL); // N*L f32 (h2)
    bf16_t* decodeb = xb;                                    // N*H bf16, reuses xb

    // 1) CSR build + dinv
    zero_int<<<(2 * NN + 255) / 256, 256, 0, stream>>>(cnt, 2 * NN);
    cnt_count<<<(EE + 255) / 256, 256, 0, stream>>>(ei, cnt, EE);
    dinv_from_cnt<<<(NN + 255) / 256, 256, 0, stream>>>(cnt, dinv, NN);
    scan_rowptr<<<1, 1024, 0, stream>>>(cnt, rowptr, NN);
    csr_fill<<<(EE + 255) / 256, 256, 0, stream>>>(ei, rowptr, cursor, csr_src, EE);

    // 2) bf16 conversions
    cvt_bf16<<<2048, 256, 0, stream>>>((const float4*)x, (ushort4*)xb, (long long)NN * DD / 4);
    {
        dim3 ga(HH / 32, DD / 32);
        cvt_transpose_bf16<<<ga, 256, 0, stream>>>(W_gc1, W1t, DD, HH);
        dim3 gb(DD / 32, HH / 32);
        cvt_transpose_bf16<<<gb, 256, 0, stream>>>(W_fc2, W2t, HH, DD);
        dim3 gc(LL / 32, HH / 32);
        cvt_transpose_bf16<<<gc, 256, 0, stream>>>(W_gc2, Wg2t, HH, LL);
        dim3 gd(HH / 32, LL / 32);
        cvt_transpose_bf16<<<gd, 256, 0, stream>>>(W_fc1, Wf1t, LL, HH);
    }

    const int MB128 = (NN + 127) / 128;   // 157
    const int MB256 = (NN + 255) / 256;   // 79

    // 3) h1b = bf16(xb @ W1t^T)   [N, H]   (256x256, BK=64, r11 schedule)
    {
        int gx = HH / 256;   // 6
        gemm_bf16_8ph<0, 0, 1><<<gx * MB256, 512, 0, stream>>>(xb, W1t, nullptr, h1b, NN, HH, DD, gx);
    }

    // 4) hiddenb = bf16(LN(relu(agg(h1b) + b_gc1)))
    gcn_agg_ln_h<<<(NN + 3) / 4, 256, 0, stream>>>(h1b, dinv, rowptr, csr_src, b_gc1, g1, be1, hiddenb, NN);

    // 5) h2 = hiddenb @ Wg2t^T    [N, L] f32 -> wsC   (MFMA 128x64)
    gemm_bf16_mfma<0, 0, 0, 64><<<MB128, 256, 0, stream>>>(hiddenb, Wg2t, nullptr, wsC, NN, LL, HH, 1);

    // 6) latent = LN(relu(agg(h2) + b_gc2)) -> output 0 (+ bf16 copy)
    gcn_agg_ln_l<<<(NN + 3) / 4, 256, 0, stream>>>(wsC, dinv, rowptr, csr_src, b_gc2, g2, be2, out_latent, latentb, NN);

    // 7) decodeb = bf16(relu(latentb @ Wf1t^T + b_fc1))  [N, H] (MFMA 128x128, K=64)
    {
        int gx = HH / 128;
        gemm_bf16_mfma<1, 1, 1, 128><<<gx * MB128, 256, 0, stream>>>(latentb, Wf1t, b_fc1, decodeb, NN, HH, LL, gx);
    }

    // 8) reconstructed = decodeb @ W2t^T + b_fc2  [N, D] -> output 1 (BK=64)
    {
        int gx = DD / 256;   // 12
        gemm_bf16_8ph<1, 0, 0><<<gx * MB256, 512, 0, stream>>>(decodeb, W2t, b_fc2, out_recon, NN, DD, HH, gx);
    }
}

// Round 16
// 747.107 us; speedup vs baseline: 5.0140x; 1.0468x over previous
//
#include <hip/hip_runtime.h>
#include <hip/hip_bf16.h>

// Problem constants (match reference)
#define NN 20000
#define EE 320000
#define DD 3072
#define HH 1536
#define LL 64

typedef unsigned short bf16_t;
typedef __attribute__((ext_vector_type(8))) __bf16 bf16x8;
typedef __attribute__((ext_vector_type(4))) float  f32x4;

__device__ __forceinline__ bf16_t f2bf(float f) {
    union { float f; unsigned u; } c; c.f = f;
    unsigned u = c.u;
    return (bf16_t)((u + 0x7fffu + ((u >> 16) & 1u)) >> 16);  // RNE (inputs finite)
}

// ---------------------------------------------------------------------------
// CSR build. edge_index is int32: src = ei[e], dst = ei[E+e].
// ---------------------------------------------------------------------------
__global__ void zero_int(int* __restrict__ p, int n) {
    int i = blockIdx.x * blockDim.x + threadIdx.x;
    if (i < n) p[i] = 0;
}

__global__ void cnt_count(const int* __restrict__ ei, int* __restrict__ cnt, int E) {
    int i = blockIdx.x * blockDim.x + threadIdx.x;
    if (i < E) atomicAdd(&cnt[ei[E + i]], 1);
}

__global__ void dinv_from_cnt(const int* __restrict__ cnt, float* __restrict__ dinv, int n) {
    int i = blockIdx.x * blockDim.x + threadIdx.x;
    if (i < n) dinv[i] = rsqrtf((float)(cnt[i] + 1));
}

// --- parallel rowptr scan (replaces single-block scan: was 1 CU serialized) ---
// (1) per-256-block sums
__global__ __launch_bounds__(256) void psum_block(const int* __restrict__ cnt,
                                                  int* __restrict__ bsum, int n)
{
    __shared__ int red[4];
    const int i = blockIdx.x * 256 + threadIdx.x;
    int v = (i < n) ? cnt[i] : 0;
#pragma unroll
    for (int off = 32; off > 0; off >>= 1) v += __shfl_down(v, off);
    const int wave = threadIdx.x >> 6, lane = threadIdx.x & 63;
    if (lane == 0) red[wave] = v;
    __syncthreads();
    if (threadIdx.x == 0) bsum[blockIdx.x] = red[0] + red[1] + red[2] + red[3];
}

// (2) one block scans the block sums (nb <= 128); writes exclusive offsets +
//     the grand total into rowptr[n].
__global__ __launch_bounds__(128) void scan_bsum(const int* __restrict__ bsum,
                                                 int* __restrict__ boff,
                                                 int* __restrict__ rowptr_end, int nb)
{
    __shared__ int s[128];
    const int tid = threadIdx.x;
    const int v = (tid < nb) ? bsum[tid] : 0;
    s[tid] = v;
    __syncthreads();
#pragma unroll
    for (int off = 1; off < 128; off <<= 1) {
        int t = (tid >= off) ? s[tid - off] : 0;
        __syncthreads();
        s[tid] += t;
        __syncthreads();
    }
    if (tid < nb) boff[tid] = s[tid] - v;       // exclusive
    if (tid == nb - 1) *rowptr_end = s[tid];    // total
}

// (3) intra-block exclusive scan + block offset
__global__ __launch_bounds__(256) void expand_scan(const int* __restrict__ cnt,
                                                   const int* __restrict__ boff,
                                                   int* __restrict__ rowptr, int n)
{
    __shared__ int s[256];
    const int tid = threadIdx.x;
    const int i = blockIdx.x * 256 + tid;
    const int v = (i < n) ? cnt[i] : 0;
    s[tid] = v;
    __syncthreads();
#pragma unroll
    for (int off = 1; off < 256; off <<= 1) {
        int t = (tid >= off) ? s[tid - off] : 0;
        __syncthreads();
        s[tid] += t;
        __syncthreads();
    }
    if (i < n) rowptr[i] = boff[blockIdx.x] + s[tid] - v;
}

__global__ void csr_fill(const int* __restrict__ ei, const int* __restrict__ rowptr,
                         int* __restrict__ cursor, int* __restrict__ csr_src, int E)
{
    int e = blockIdx.x * blockDim.x + threadIdx.x;
    if (e < E) {
        int d = ei[E + e];
        int pos = rowptr[d] + atomicAdd(&cursor[d], 1);
        csr_src[pos] = ei[e];
    }
}

// ---------------------------------------------------------------------------
// fp32 -> bf16 cast (vectorized), and fp32 [R][C] -> bf16 [C][R] transpose
// ---------------------------------------------------------------------------
__global__ void cvt_bf16(const float4* __restrict__ in, ushort4* __restrict__ out, long long n4) {
    for (long long i = (long long)blockIdx.x * blockDim.x + threadIdx.x;
         i < n4; i += (long long)gridDim.x * blockDim.x) {
        float4 v = in[i];
        ushort4 o;
        o.x = f2bf(v.x); o.y = f2bf(v.y); o.z = f2bf(v.z); o.w = f2bf(v.w);
        out[i] = o;
    }
}

__global__ __launch_bounds__(256) void cvt_transpose_bf16(
    const float* __restrict__ in, bf16_t* __restrict__ out, int R, int C)
{
    __shared__ float tile[32][33];
    const int bx = blockIdx.x, by = blockIdx.y;   // bx over C/32, by over R/32
    const int tx = threadIdx.x & 31;
    const int ty = (threadIdx.x >> 5) * 4;
#pragma unroll
    for (int j = 0; j < 4; ++j)
        tile[ty + j][tx] = in[(long long)(by * 32 + ty + j) * C + bx * 32 + tx];
    __syncthreads();
#pragma unroll
    for (int j = 0; j < 4; ++j)
        out[(long long)(bx * 32 + ty + j) * R + by * 32 + tx] = f2bf(tile[tx][ty + j]);
}

#define GLOAD_LDS16(g, l)                                                     \
    __builtin_amdgcn_global_load_lds(                                         \
        (const __attribute__((address_space(1))) unsigned int*)(g),          \
        (__attribute__((address_space(3))) unsigned int*)(l), 16, 0, 0)

// ---------------------------------------------------------------------------
// 256x256 BF16 MFMA GEMM, BK=64 double-buffer (128 KiB LDS), 4 phases/tile,
// snake order, ONE-PHASE-AHEAD register prefetch (best-measured: ~232 us,
// MfmaUtil ~35.5%, 813 TF at this shape). Reads/tile/wave = 20,4,0,0 = 24.
//   P1(0,0): rd A0,B0 + prefetch A1; stage (o).A1<-t+1
//   P2(1,0): prefetch B1;            stage (o).B1<-t+1
//   P3(1,1): no reads;               stage (c).A0<-t+2
//   P4(0,1): no reads;               stage (c).B0<-t+2; vmcnt(4)
// NOTE (r14 lesson): acc alone = 128 VGPR/lane at this tile -> 2 waves/SIMD
// is the occupancy ceiling; do NOT force higher via __launch_bounds__.
// ---------------------------------------------------------------------------
#define MFMA16(a, b, c) __builtin_amdgcn_mfma_f32_16x16x32_bf16((a), (b), (c), 0, 0, 0)

#define LDA_F(CUR, MH, MF, KS)                                                \
    (*(const bf16x8*)((const char*)(&lds[(CUR)][0][(MH)][0]) +                \
        (arow + (MF) * 16) * 128 + ((KS) ? offk1 : offk0)))
#define LDB_F(CUR, NH, NF, KS)                                                \
    (*(const bf16x8*)((const char*)(&lds[(CUR)][1][(NH)][0]) +                \
        (brw + (NF) * 16) * 128 + ((KS) ? offk1 : offk0)))

#define READ_AQ(DST, CUR, MH)                                                  \
    _Pragma("unroll")                                                          \
    for (int mf = 0; mf < 4; ++mf) {                                           \
        DST[mf][0] = LDA_F(CUR, MH, mf, 0);                                    \
        DST[mf][1] = LDA_F(CUR, MH, mf, 1);                                    \
    }

#define READ_BQ(DST, CUR, NH)                                                  \
    _Pragma("unroll")                                                          \
    for (int nf = 0; nf < 2; ++nf) {                                           \
        DST[nf][0] = LDB_F(CUR, NH, nf, 0);                                    \
        DST[nf][1] = LDB_F(CUR, NH, nf, 1);                                    \
    }

#define MFMA_Q(MH, NH, PA, PB)                                                 \
    do {                                                                       \
        __builtin_amdgcn_s_setprio(1);                                         \
        _Pragma("unroll")                                                      \
        for (int mf = 0; mf < 4; ++mf) {                                       \
            _Pragma("unroll")                                                  \
            for (int nf = 0; nf < 2; ++nf) {                                   \
                acc[MH][NH][mf][nf] = MFMA16(PA[mf][0], PB[nf][0], acc[MH][NH][mf][nf]); \
                acc[MH][NH][mf][nf] = MFMA16(PA[mf][1], PB[nf][1], acc[MH][NH][mf][nf]); \
            }                                                                  \
        }                                                                      \
        __builtin_amdgcn_s_setprio(0);                                         \
    } while (0)

template <int HAS_BIAS, int RELU, int OUT_BF16>
__global__ __launch_bounds__(512, 2) void gemm_bf16_8ph(
    const bf16_t* __restrict__ A, const bf16_t* __restrict__ Bt,
    const float* __restrict__ bias, void* __restrict__ Cout,
    int M, int N, int K, int gx)
{
    __shared__ bf16_t lds[2][2][2][8192];   // [buf][A/B][half][128 rows x 64 k] = 128 KiB

    // bijective XCD chunk swizzle
    const int nwg = gridDim.x;
    const int q = nwg >> 3, r = nwg & 7;
    const int xcd = blockIdx.x & 7, lo = blockIdx.x >> 3;
    const int wgid = (xcd < r ? xcd * (q + 1) : r * (q + 1) + (xcd - r) * q) + lo;
    const int brow = (wgid / gx) * 256;
    const int bcol = (wgid % gx) * 256;

    const int tid = threadIdx.x;
    const int w = tid >> 6, l = tid & 63;
    const int wr = w >> 2, wc = w & 3;     // 2 x 4 wave grid
    const int nt = K >> 6;                 // BK=64 tiles

    f32x4 acc[2][2][4][2] = {};

    // staging lane constants: chunk c = w*2+i covers rows c*8..c*8+7 (1 KiB)
    const int srow8 = l >> 3;                         // row within chunk
    const int swz8  = (((l & 7) ^ (l >> 3)) << 3);    // swizzled k-slot (bf16 units)

    auto stage_a = [&](int buf, int h, int s) {
#pragma unroll
        for (int i = 0; i < 2; ++i) {
            const int c = (w << 1) + i;
            int grow = brow + h * 128 + c * 8 + srow8;
            if (grow > M - 1) grow = M - 1;           // clamp (in-bounds dup read)
            const bf16_t* g = A + (long long)grow * K + (s << 6) + swz8;
            GLOAD_LDS16(g, &lds[buf][0][h][c * 512]);
        }
    };
    auto stage_b = [&](int buf, int h, int s) {
#pragma unroll
        for (int i = 0; i < 2; ++i) {
            const int c = (w << 1) + i;
            const int grow = bcol + h * 128 + c * 8 + srow8;   // N%256==0, no clamp
            const bf16_t* g = Bt + (long long)grow * K + (s << 6) + swz8;
            GLOAD_LDS16(g, &lds[buf][1][h][c * 512]);
        }
    };

    // ds_read address constants (read-side swizzle: same involution)
    const int arow  = wr * 64 + (l & 15);
    const int brw   = wc * 32 + (l & 15);
    const int xm    = (l & 7) << 4;
    const int offk0 = ((l >> 4) << 4) ^ xm;
    const int offk1 = (((l >> 4) << 4) + 64) ^ xm;

    // prologue: tile0 complete (8 loads) + tile1 A0,B0 (4 loads);
    // vmcnt(4) -> tile0 landed, tile1 A0,B0 in flight (steady-state invariant)
    stage_a(0, 0, 0); stage_b(0, 0, 0);
    stage_a(0, 1, 0); stage_b(0, 1, 0);
    stage_a(1, 0, 1); stage_b(1, 0, 1);
    __builtin_amdgcn_sched_barrier(0);
    asm volatile("s_waitcnt vmcnt(4)" ::: "memory");
    __builtin_amdgcn_sched_barrier(0);
    __builtin_amdgcn_s_barrier();

    int cur = 0;
    for (int t = 0; t < nt; ++t) {
        const int t1 = (t + 1 < nt) ? t + 1 : nt - 1;
        const int t2 = (t + 2 < nt) ? t + 2 : nt - 1;
        bf16x8 pa0[4][2], pa1[4][2], pb0[2][2], pb1[2][2];

        // P1 (0,0): read A0+B0 (own) + prefetch A1; stage (o).A1 <- t+1
        __builtin_amdgcn_sched_barrier(0);
        READ_AQ(pa0, cur, 0);
        READ_BQ(pb0, cur, 0);
        READ_AQ(pa1, cur, 1);              // prefetch for P2 (valid since t-1)
        stage_a(cur ^ 1, 1, t1);
        MFMA_Q(0, 0, pa0, pb0);
        __builtin_amdgcn_s_barrier();

        // P2 (1,0): prefetch B1 for P3; stage (o).B1 <- t+1
        __builtin_amdgcn_sched_barrier(0);
        READ_BQ(pb1, cur, 1);              // prefetch for P3 (valid since t-1)
        stage_b(cur ^ 1, 1, t1);
        MFMA_Q(1, 0, pa1, pb0);
        __builtin_amdgcn_s_barrier();

        // P3 (1,1): no reads; stage (cur).A0 <- t+2 (last read of A0 was t.P1)
        __builtin_amdgcn_sched_barrier(0);
        stage_a(cur, 0, t2);
        MFMA_Q(1, 1, pa1, pb1);
        __builtin_amdgcn_s_barrier();

        // P4 (0,1): no reads; stage (cur).B0 <- t+2; counted vmcnt
        __builtin_amdgcn_sched_barrier(0);
        stage_b(cur, 0, t2);
        MFMA_Q(0, 1, pa0, pb1);
        asm volatile("s_waitcnt vmcnt(4)" ::: "memory");
        __builtin_amdgcn_sched_barrier(0);
        __builtin_amdgcn_s_barrier();

        cur ^= 1;
    }

    // epilogue: C/D layout col=lane&15, row=(lane>>4)*4+j per 16x16 frag
#pragma unroll
    for (int mh = 0; mh < 2; ++mh) {
#pragma unroll
        for (int nh = 0; nh < 2; ++nh) {
#pragma unroll
            for (int nf = 0; nf < 2; ++nf) {
                const int col = bcol + nh * 128 + wc * 32 + nf * 16 + (l & 15);
                const float bv = HAS_BIAS ? bias[col] : 0.0f;
#pragma unroll
                for (int mf = 0; mf < 4; ++mf) {
#pragma unroll
                    for (int j = 0; j < 4; ++j) {
                        const int row = brow + mh * 128 + wr * 64 + mf * 16 + (l >> 4) * 4 + j;
                        if (row < M) {
                            float v = acc[mh][nh][mf][nf][j] + bv;
                            if (RELU) v = fmaxf(v, 0.0f);
                            if (OUT_BF16) ((bf16_t*)Cout)[(long long)row * N + col] = f2bf(v);
                            else          ((float*)Cout)[(long long)row * N + col] = v;
                        }
                    }
                }
            }
        }
    }
}

// ---------------------------------------------------------------------------
// m97-structure BF16 MFMA GEMM (kept for the two small GEMMs):
// C[M,N] = A[M,K] @ Bt[N,K]^T (+bias)(+relu), fp32 or bf16 out.
// ---------------------------------------------------------------------------
template <int HAS_BIAS, int RELU, int OUT_BF16, int BNT>
__global__ __launch_bounds__(256) void gemm_bf16_mfma(
    const bf16_t* __restrict__ A, const bf16_t* __restrict__ Bt,
    const float* __restrict__ bias, void* __restrict__ Cout,
    int M, int N, int K, int gx)
{
    constexpr int NFRAG = BNT / 32;
    constexpr int BHALF = BNT / 64;
    constexpr int WCOFF = BNT / 2;

    __shared__ bf16_t As[128 * 32];
    __shared__ bf16_t Bs[BNT * 32];

    const int nwg = gridDim.x;
    const int q = nwg >> 3, r = nwg & 7;
    const int xcd = blockIdx.x & 7, lo = blockIdx.x >> 3;
    const int wgid = (xcd < r ? xcd * (q + 1) : r * (q + 1) + (xcd - r) * q) + lo;
    const int brow = (wgid / gx) * 128;
    const int bcol = (wgid % gx) * BNT;

    const int tid = threadIdx.x;
    const int w   = tid >> 6;
    const int l   = tid & 63;
    const int wr  = w >> 1, wc = w & 1;

    f32x4 acc[4][NFRAG] = {};

    const int srow   = tid >> 2;
    const int schunk = (tid & 3) * 8;

    for (int k0 = 0; k0 < K; k0 += 32) {
#pragma unroll
        for (int half = 0; half < 2; ++half) {
            int gr = brow + half * 64 + srow;
            if (gr > M - 1) gr = M - 1;
            const bf16_t* gsrc = A + (long long)gr * K + k0 + schunk;
            GLOAD_LDS16(gsrc, &As[(half * 64 + w * 16) * 32]);
        }
#pragma unroll
        for (int half = 0; half < BHALF; ++half) {
            int rr = half * 64 + srow;
            const bf16_t* gsrc = Bt + (long long)(bcol + rr) * K + k0 + schunk;
            GLOAD_LDS16(gsrc, &Bs[(half * 64 + w * 16) * 32]);
        }
        __syncthreads();

        bf16x8 af[4], bfr[NFRAG];
#pragma unroll
        for (int m = 0; m < 4; ++m) {
            int row = wr * 64 + m * 16 + (l & 15);
            af[m] = *(const bf16x8*)&As[row * 32 + (l >> 4) * 8];
        }
#pragma unroll
        for (int n = 0; n < NFRAG; ++n) {
            int row = wc * WCOFF + n * 16 + (l & 15);
            bfr[n] = *(const bf16x8*)&Bs[row * 32 + (l >> 4) * 8];
        }
#pragma unroll
        for (int m = 0; m < 4; ++m)
#pragma unroll
            for (int n = 0; n < NFRAG; ++n)
                acc[m][n] = MFMA16(af[m], bfr[n], acc[m][n]);
        __syncthreads();
    }

#pragma unroll
    for (int m = 0; m < 4; ++m) {
#pragma unroll
        for (int n = 0; n < NFRAG; ++n) {
            int col = bcol + wc * WCOFF + n * 16 + (l & 15);
            float b = HAS_BIAS ? bias[col] : 0.0f;
#pragma unroll
            for (int j = 0; j < 4; ++j) {
                int row = brow + wr * 64 + m * 16 + (l >> 4) * 4 + j;
                if (row < M) {
                    float v = acc[m][n][j] + b;
                    if (RELU) v = fmaxf(v, 0.0f);
                    if (OUT_BF16) ((bf16_t*)Cout)[(long long)row * N + col] = f2bf(v);
                    else          ((float*)Cout)[(long long)row * N + col] = v;
                }
            }
        }
    }
}

// ---------------------------------------------------------------------------
// Fused GCN aggregation (CSR gather, bf16 h) + bias + ReLU + LN, F = 1536.
// One WAVE per dst row (4 rows/block); lane owns 3 bf16x8 chunks (24 feats).
// 2-edge ILP: two independent src-row load chains per iteration.
// ---------------------------------------------------------------------------
__global__ __launch_bounds__(256) void gcn_agg_ln_h(
    const bf16_t* __restrict__ h, const float* __restrict__ dinv,
    const int* __restrict__ rowptr, const int* __restrict__ csr_src,
    const float* __restrict__ bias, const float* __restrict__ g,
    const float* __restrict__ be, bf16_t* __restrict__ out, int n)
{
    const int row  = blockIdx.x * 4 + (threadIdx.x >> 6);
    const int lane = threadIdx.x & 63;
    if (row >= n) return;
    const float dd = dinv[row];

    float acc[24];
    {
        const bf16x8* hr = (const bf16x8*)(h + (long long)row * HH);
#pragma unroll
        for (int c = 0; c < 3; ++c) {
            bf16x8 v = hr[c * 64 + lane];
#pragma unroll
            for (int j = 0; j < 8; ++j) acc[c * 8 + j] = dd * (float)v[j];
        }
    }
    const int s0 = rowptr[row], s1 = rowptr[row + 1];
    int k = s0;
    for (; k + 1 < s1; k += 2) {
        const int sa = csr_src[k];
        const int sb = csr_src[k + 1];
        const float wa = dinv[sa];
        const float wb = dinv[sb];
        const bf16x8* ha = (const bf16x8*)(h + (long long)sa * HH);
        const bf16x8* hb = (const bf16x8*)(h + (long long)sb * HH);
        bf16x8 va[3], vb[3];
#pragma unroll
        for (int c = 0; c < 3; ++c) { va[c] = ha[c * 64 + lane]; vb[c] = hb[c * 64 + lane]; }
#pragma unroll
        for (int c = 0; c < 3; ++c)
#pragma unroll
            for (int j = 0; j < 8; ++j)
                acc[c * 8 + j] += wa * (float)va[c][j] + wb * (float)vb[c][j];
    }
    if (k < s1) {
        const int s = csr_src[k];
        const float wv = dinv[s];
        const bf16x8* hs = (const bf16x8*)(h + (long long)s * HH);
#pragma unroll
        for (int c = 0; c < 3; ++c) {
            bf16x8 v = hs[c * 64 + lane];
#pragma unroll
            for (int j = 0; j < 8; ++j) acc[c * 8 + j] += wv * (float)v[j];
        }
    }

    float lsum = 0.0f, lsq = 0.0f;
#pragma unroll
    for (int c = 0; c < 3; ++c)
#pragma unroll
        for (int j = 0; j < 8; ++j) {
            int idx = c * 512 + lane * 8 + j;
            float v = fmaxf(acc[c * 8 + j] * dd + bias[idx], 0.0f);
            acc[c * 8 + j] = v;
            lsum += v;
            lsq  += v * v;
        }
#pragma unroll
    for (int off = 32; off > 0; off >>= 1) {
        lsum += __shfl_xor(lsum, off);
        lsq  += __shfl_xor(lsq,  off);
    }
    const float mean = lsum / HH;
    const float var  = lsq / HH - mean * mean;
    const float rstd = rsqrtf(var + 1e-5f);

    bf16_t* y = out + (long long)row * HH;
#pragma unroll
    for (int c = 0; c < 3; ++c)
#pragma unroll
        for (int j = 0; j < 8; ++j) {
            int idx = c * 512 + lane * 8 + j;
            y[idx] = f2bf((acc[c * 8 + j] - mean) * rstd * g[idx] + be[idx]);
        }
}

// Same, F = 64 (fp32 h): writes fp32 latent (output 0) AND bf16 copy.
__global__ __launch_bounds__(256) void gcn_agg_ln_l(
    const float* __restrict__ h, const float* __restrict__ dinv,
    const int* __restrict__ rowptr, const int* __restrict__ csr_src,
    const float* __restrict__ bias, const float* __restrict__ g,
    const float* __restrict__ be, float* __restrict__ out,
    bf16_t* __restrict__ outb, int n)
{
    const int row  = blockIdx.x * 4 + (threadIdx.x >> 6);
    const int lane = threadIdx.x & 63;
    if (row >= n) return;
    const float dd = dinv[row];

    float acc = dd * h[(long long)row * LL + lane];
    const int s0 = rowptr[row], s1 = rowptr[row + 1];
    for (int k = s0; k < s1; ++k) {
        const int s = csr_src[k];
        acc += dinv[s] * h[(long long)s * LL + lane];
    }
    float v = fmaxf(acc * dd + bias[lane], 0.0f);
    float lsum = v, lsq = v * v;
#pragma unroll
    for (int off = 32; off > 0; off >>= 1) {
        lsum += __shfl_xor(lsum, off);
        lsq  += __shfl_xor(lsq,  off);
    }
    const float mean = lsum / LL;
    const float var  = lsq / LL - mean * mean;
    const float rstd = rsqrtf(var + 1e-5f);
    float o = (v - mean) * rstd * g[lane] + be[lane];
    out[(long long)row * LL + lane]  = o;
    outb[(long long)row * LL + lane] = f2bf(o);
}

// ---------------------------------------------------------------------------
// Launch.
// ---------------------------------------------------------------------------
extern "C" void kernel_launch(void* const* d_in, const int* in_sizes, int n_in,
                              void* d_out, int out_size, void* d_ws, size_t ws_size,
                              hipStream_t stream)
{
    const float* x     = (const float*)d_in[0];
    const int*   ei    = (const int*)d_in[1];
    const float* W_gc1 = (const float*)d_in[2];
    const float* b_gc1 = (const float*)d_in[3];
    const float* W_gc2 = (const float*)d_in[4];
    const float* b_gc2 = (const float*)d_in[5];
    const float* g1    = (const float*)d_in[6];
    const float* be1   = (const float*)d_in[7];
    const float* g2    = (const float*)d_in[8];
    const float* be2   = (const float*)d_in[9];
    const float* W_fc1 = (const float*)d_in[10];
    const float* b_fc1 = (const float*)d_in[11];
    const float* W_fc2 = (const float*)d_in[12];
    const float* b_fc2 = (const float*)d_in[13];

    float* out_latent = (float*)d_out;                       // [N, L]
    float* out_recon  = (float*)d_out + (long long)NN * LL;  // [N, D]

    bf16_t* h1b     = (bf16_t*)out_recon;                         // N*H bf16
    bf16_t* hiddenb = (bf16_t*)(out_recon + (long long)NN * HH);  // N*H bf16 (2nd half)

    const int NB = (NN + 255) / 256;   // 79 scan blocks

    float*  dinv    = (float*)d_ws;                          // N
    int*    cnt     = (int*)(dinv + NN);                     // N
    int*    cursor  = cnt + NN;                              // N
    int*    rowptr  = cursor + NN;                           // N+1
    int*    csr_src = rowptr + NN + 1;                       // E
    int*    bsum    = csr_src + EE;                          // NB (<=128)
    int*    boff    = bsum + 128;                            // NB (<=128)
    char*   pbase   = (char*)(boff + 128);
    pbase = (char*)(((size_t)pbase + 255) & ~(size_t)255);
    bf16_t* xb      = (bf16_t*)pbase;                        // N*D bf16 (later decodeb)
    bf16_t* W1t     = xb + (long long)NN * DD;               // H*D bf16 (W_gc1^T)
    bf16_t* W2t     = W1t + (long long)DD * HH;              // D*H bf16 (W_fc2^T)
    bf16_t* Wg2t    = W2t + (long long)DD * HH;              // L*H bf16 (W_gc2^T)
    bf16_t* Wf1t    = Wg2t + (long long)HH * LL;             // H*L bf16 (W_fc1^T)
    bf16_t* latentb = Wf1t + (long long)LL * HH;             // N*L bf16
    float*  wsC     = (float*)(latentb + (long long)NN * LL); // N*L f32 (h2)
    bf16_t* decodeb = xb;                                    // N*H bf16, reuses xb

    // 1) CSR build + dinv (parallel rowptr scan: psum -> scan -> expand)
    zero_int<<<(2 * NN + 255) / 256, 256, 0, stream>>>(cnt, 2 * NN);  // cnt + cursor
    cnt_count<<<(EE + 255) / 256, 256, 0, stream>>>(ei, cnt, EE);
    dinv_from_cnt<<<(NN + 255) / 256, 256, 0, stream>>>(cnt, dinv, NN);
    psum_block<<<NB, 256, 0, stream>>>(cnt, bsum, NN);
    scan_bsum<<<1, 128, 0, stream>>>(bsum, boff, rowptr + NN, NB);
    expand_scan<<<NB, 256, 0, stream>>>(cnt, boff, rowptr, NN);
    csr_fill<<<(EE + 255) / 256, 256, 0, stream>>>(ei, rowptr, cursor, csr_src, EE);

    // 2) bf16 conversions
    cvt_bf16<<<2048, 256, 0, stream>>>((const float4*)x, (ushort4*)xb, (long long)NN * DD / 4);
    {
        dim3 ga(HH / 32, DD / 32);
        cvt_transpose_bf16<<<ga, 256, 0, stream>>>(W_gc1, W1t, DD, HH);
        dim3 gb(DD / 32, HH / 32);
        cvt_transpose_bf16<<<gb, 256, 0, stream>>>(W_fc2, W2t, HH, DD);
        dim3 gc(LL / 32, HH / 32);
        cvt_transpose_bf16<<<gc, 256, 0, stream>>>(W_gc2, Wg2t, HH, LL);
        dim3 gd(HH / 32, LL / 32);
        cvt_transpose_bf16<<<gd, 256, 0, stream>>>(W_fc1, Wf1t, LL, HH);
    }

    const int MB128 = (NN + 127) / 128;   // 157
    const int MB256 = (NN + 255) / 256;   // 79

    // 3) h1b = bf16(xb @ W1t^T)   [N, H]   (256x256, BK=64, r11 schedule)
    {
        int gx = HH / 256;   // 6
        gemm_bf16_8ph<0, 0, 1><<<gx * MB256, 512, 0, stream>>>(xb, W1t, nullptr, h1b, NN, HH, DD, gx);
    }

    // 4) hiddenb = bf16(LN(relu(agg(h1b) + b_gc1)))
    gcn_agg_ln_h<<<(NN + 3) / 4, 256, 0, stream>>>(h1b, dinv, rowptr, csr_src, b_gc1, g1, be1, hiddenb, NN);

    // 5) h2 = hiddenb @ Wg2t^T    [N, L] f32 -> wsC   (MFMA 128x64)
    gemm_bf16_mfma<0, 0, 0, 64><<<MB128, 256, 0, stream>>>(hiddenb, Wg2t, nullptr, wsC, NN, LL, HH, 1);

    // 6) latent = LN(relu(agg(h2) + b_gc2)) -> output 0 (+ bf16 copy)
    gcn_agg_ln_l<<<(NN + 3) / 4, 256, 0, stream>>>(wsC, dinv, rowptr, csr_src, b_gc2, g2, be2, out_latent, latentb, NN);

    // 7) decodeb = bf16(relu(latentb @ Wf1t^T + b_fc1))  [N, H] (MFMA 128x128, K=64)
    {
        int gx = HH / 128;
        gemm_bf16_mfma<1, 1, 1, 128><<<gx * MB128, 256, 0, stream>>>(latentb, Wf1t, b_fc1, decodeb, NN, HH, LL, gx);
    }

    // 8) reconstructed = decodeb @ W2t^T + b_fc2  [N, D] -> output 1 (BK=64)
    {
        int gx = DD / 256;   // 12
        gemm_bf16_8ph<1, 0, 0><<<gx * MB256, 512, 0, stream>>>(decodeb, W2t, b_fc2, out_recon, NN, DD, HH, gx);
    }
}